// Round 1
// baseline (1690.817 us; speedup 1.0000x reference)
//
#include <hip/hip_runtime.h>

namespace {

constexpr int Bn = 4, Cn = 3, Hn = 1080, Wn = 1920;
constexpr int HW = Hn * Wn;
constexpr float kAlpha = 0.1f;

// One thread per output pixel (b, py, px); processes all 3 channels.
// Bicubic 5-tap Catmull-Rom reduces to 12 texels/channel because taps 1-4
// have an exact-integer coordinate on one axis (tc0/tc3 hit texel centers).
__global__ __launch_bounds__(128)
void taa_kernel(const float* __restrict__ xin,
                const float2* __restrict__ mv,
                const float* __restrict__ hist,
                float* __restrict__ out)
{
    const int px = blockIdx.x * 128 + threadIdx.x;   // Wn = 15 * 128 exactly
    const int py = blockIdx.y;
    const int b  = blockIdx.z;
    const int p  = py * Wn + px;

    const float2 g = mv[(size_t)b * HW + p];

    // pos = (grid + 1) * 0.5 * size ; cpos = floor(pos - 0.5) + 0.5 ; f = pos - cpos
    const float posx = (g.x + 1.0f) * 0.5f * (float)Wn;
    const float posy = (g.y + 1.0f) * 0.5f * (float)Hn;
    const float Xf = floorf(posx - 0.5f);
    const float Yf = floorf(posy - 0.5f);
    const float fx = posx - (Xf + 0.5f);
    const float fy = posy - (Yf + 0.5f);

    // Catmull-Rom weights per axis
    const float fx2 = fx * fx, fx3 = fx2 * fx;
    const float w0x = -0.5f * fx3 + fx2 - 0.5f * fx;
    const float w1x =  1.5f * fx3 - 2.5f * fx2 + 1.0f;
    const float w2x = -1.5f * fx3 + 2.0f * fx2 + 0.5f * fx;
    const float w3x =  0.5f * fx3 - 0.5f * fx2;
    const float w12x = w1x + w2x;          // >= 1 always, safe divide
    const float bxr  = w2x / w12x;         // fractional offset of tc12.x

    const float fy2 = fy * fy, fy3 = fy2 * fy;
    const float w0y = -0.5f * fy3 + fy2 - 0.5f * fy;
    const float w1y =  1.5f * fy3 - 2.5f * fy2 + 1.0f;
    const float w2y = -1.5f * fy3 + 2.0f * fy2 + 0.5f * fy;
    const float w3y =  0.5f * fy3 - 0.5f * fy2;
    const float w12y = w1y + w2y;
    const float byr  = w2y / w12y;

    const int X = (int)Xf;
    const int Y = (int)Yf;

    // zero-padding validity (matches grid_sample padding_mode='zeros')
    const float vxm1 = ((unsigned)(X - 1) < (unsigned)Wn) ? 1.0f : 0.0f;
    const float vx0  = ((unsigned)(X    ) < (unsigned)Wn) ? 1.0f : 0.0f;
    const float vx1  = ((unsigned)(X + 1) < (unsigned)Wn) ? 1.0f : 0.0f;
    const float vx2  = ((unsigned)(X + 2) < (unsigned)Wn) ? 1.0f : 0.0f;
    const float vym1 = ((unsigned)(Y - 1) < (unsigned)Hn) ? 1.0f : 0.0f;
    const float vy0  = ((unsigned)(Y    ) < (unsigned)Hn) ? 1.0f : 0.0f;
    const float vy1  = ((unsigned)(Y + 1) < (unsigned)Hn) ? 1.0f : 0.0f;
    const float vy2  = ((unsigned)(Y + 2) < (unsigned)Hn) ? 1.0f : 0.0f;

    // clamped coordinates (weight==0 makes OOB loads harmless)
    const int cxm1 = min(max(X - 1, 0), Wn - 1);
    const int cx0  = min(max(X,     0), Wn - 1);
    const int cx1  = min(max(X + 1, 0), Wn - 1);
    const int cx2  = min(max(X + 2, 0), Wn - 1);
    const int rym1 = min(max(Y - 1, 0), Hn - 1) * Wn;
    const int ry0  = min(max(Y,     0), Hn - 1) * Wn;
    const int ry1  = min(max(Y + 1, 0), Hn - 1) * Wn;
    const int ry2  = min(max(Y + 2, 0), Hn - 1) * Wn;

    // tap scalar weights
    const float k1 = w12x * w0y;   // (tc12.x, tc0.y)  -> row Y-1, x-bilinear
    const float k2 = w0x * w12y;   // (tc0.x, tc12.y)  -> col X-1, y-bilinear
    const float k3 = w3x * w12y;   // (tc3.x, tc12.y)  -> col X+2, y-bilinear
    const float k4 = w12x * w3y;   // (tc12.x, tc3.y)  -> row Y+2, x-bilinear
    const float k5 = w12x * w12y;  // (tc12.x, tc12.y) -> full bilinear
    const float inv_denom = 1.0f / (k1 + k2 + k3 + k4 + k5);  // denom >= 1

    const float wxl = 1.0f - bxr, wxh = bxr;
    const float wyl = 1.0f - byr, wyh = byr;

    // per-texel folded weights (tap weight x bilinear weight x validity)
    const float wA = k1 * wxl * (vym1 * vx0);
    const float wB = k1 * wxh * (vym1 * vx1);
    const float wC = k2 * wyl * (vxm1 * vy0);
    const float wD = k2 * wyh * (vxm1 * vy1);
    const float wE = k3 * wyl * (vx2 * vy0);
    const float wF = k3 * wyh * (vx2 * vy1);
    const float wG = k4 * wxl * (vy2 * vx0);
    const float wH = k4 * wxh * (vy2 * vx1);
    const float wI = k5 * wxl * wyl * (vx0 * vy0);
    const float wJ = k5 * wxh * wyl * (vx1 * vy0);
    const float wK = k5 * wxl * wyh * (vx0 * vy1);
    const float wL = k5 * wxh * wyh * (vx1 * vy1);

    const int oA = rym1 + cx0,  oB = rym1 + cx1;
    const int oC = ry0  + cxm1, oD = ry1  + cxm1;
    const int oE = ry0  + cx2,  oF = ry1  + cx2;
    const int oG = ry2  + cx0,  oH = ry2  + cx1;
    const int oI = ry0  + cx0,  oJ = ry0  + cx1;
    const int oK = ry1  + cx0,  oL = ry1  + cx1;

    // 3x3 pool offsets; clamping duplicates edge texels, harmless for min/max
    const int pym = max(py - 1, 0) * Wn;
    const int py0 = py * Wn;
    const int pyp = min(py + 1, Hn - 1) * Wn;
    const int pxm = max(px - 1, 0);
    const int pxp = min(px + 1, Wn - 1);

    #pragma unroll
    for (int c = 0; c < Cn; ++c) {
        const size_t plane = (size_t)(b * Cn + c) * HW;
        const float* __restrict__ hp = hist + plane;

        float acc = wA * hp[oA];
        acc = fmaf(wB, hp[oB], acc);
        acc = fmaf(wC, hp[oC], acc);
        acc = fmaf(wD, hp[oD], acc);
        acc = fmaf(wE, hp[oE], acc);
        acc = fmaf(wF, hp[oF], acc);
        acc = fmaf(wG, hp[oG], acc);
        acc = fmaf(wH, hp[oH], acc);
        acc = fmaf(wI, hp[oI], acc);
        acc = fmaf(wJ, hp[oJ], acc);
        acc = fmaf(wK, hp[oK], acc);
        acc = fmaf(wL, hp[oL], acc);

        float rep = acc * inv_denom;
        rep = fminf(fmaxf(rep, 0.0f), 1.0f);

        const float* __restrict__ xp = xin + plane;
        const float r0a = xp[pym + pxm], r0b = xp[pym + px], r0c = xp[pym + pxp];
        const float r1a = xp[py0 + pxm], r1b = xp[py0 + px], r1c = xp[py0 + pxp];
        const float r2a = xp[pyp + pxm], r2b = xp[pyp + px], r2c = xp[pyp + pxp];

        const float mx = fmaxf(fmaxf(fmaxf(r0a, r0b), fmaxf(r0c, r1a)),
                               fmaxf(fmaxf(r1b, r1c), fmaxf(fmaxf(r2a, r2b), r2c)));
        const float mn = fminf(fminf(fminf(r0a, r0b), fminf(r0c, r1a)),
                               fminf(fminf(r1b, r1c), fminf(fminf(r2a, r2b), r2c)));

        rep = fminf(fmaxf(rep, mn), mx);   // neighborhood clamp
        out[plane + p] = kAlpha * r1b + (1.0f - kAlpha) * rep;
    }
}

} // namespace

extern "C" void kernel_launch(void* const* d_in, const int* in_sizes, int n_in,
                              void* d_out, int out_size, void* d_ws, size_t ws_size,
                              hipStream_t stream) {
    const float*  x    = (const float*)d_in[0];
    const float2* mv   = (const float2*)d_in[1];
    const float*  hist = (const float*)d_in[2];
    float* outp = (float*)d_out;

    dim3 grid(Wn / 128, Hn, Bn);   // 15 x 1080 x 4, exact coverage
    dim3 block(128, 1, 1);
    taa_kernel<<<grid, block, 0, stream>>>(x, mv, hist, outp);
}

// Round 2
// 629.716 us; speedup vs baseline: 2.6850x; 2.6850x over previous
//
#include <hip/hip_runtime.h>

namespace {

constexpr int Bn = 4, Cn = 3, Hn = 1080, Wn = 1920;
constexpr int HW = Hn * Wn;
constexpr float kAlpha = 0.1f;
constexpr float kInv2047 = 1.0f / 2047.0f;
constexpr float kInv1023 = 1.0f / 1023.0f;

typedef float v2f __attribute__((ext_vector_type(2)));

// ---- repack: planar RGB float -> one dword/texel, R11 G11 B10 fixed point ----
__global__ __launch_bounds__(256)
void pack_kernel(const float* __restrict__ hist, unsigned int* __restrict__ packed)
{
    const int i = blockIdx.x * 256 + threadIdx.x;   // Bn*HW = 256 * 32400 exactly
    const int b = i / HW;
    const int p = i - b * HW;
    const float* __restrict__ base = hist + (size_t)b * Cn * HW + p;
    const float r  = base[0];
    const float g  = base[HW];
    const float bl = base[2 * HW];
    const unsigned R  = (unsigned)(fminf(fmaxf(r,  0.0f), 1.0f) * 2047.0f + 0.5f);
    const unsigned G  = (unsigned)(fminf(fmaxf(g,  0.0f), 1.0f) * 2047.0f + 0.5f);
    const unsigned Bq = (unsigned)(fminf(fmaxf(bl, 0.0f), 1.0f) * 1023.0f + 0.5f);
    packed[i] = (R << 21) | (G << 10) | Bq;
}

// ---- main TAA kernel; PACKED gathers from the packed texture (12 loads for
// all 3 channels), fallback gathers 36 planar floats ----
template <bool PACKED>
__global__ __launch_bounds__(128)
void taa_main(const float* __restrict__ xin,
              const v2f* __restrict__ mv,
              const float* __restrict__ hist,
              const unsigned int* __restrict__ packed,
              float* __restrict__ out)
{
    // batch = bid & 3 so round-robin block->XCD (i%8) pins batch b to XCDs {b,b+4}:
    // each XCD's 4MB L2 holds exactly one batch's ~2.1MB gather working set.
    const int bid = blockIdx.x;
    const int b   = bid & 3;
    const int r   = bid >> 2;              // 0 .. 15*1080-1
    const int py  = r / 15;
    const int px  = (r - py * 15) * 128 + threadIdx.x;
    const int p   = py * Wn + px;

    const v2f g = __builtin_nontemporal_load(&mv[(size_t)b * HW + p]);

    const float posx = (g.x + 1.0f) * 0.5f * (float)Wn;
    const float posy = (g.y + 1.0f) * 0.5f * (float)Hn;
    const float Xf = floorf(posx - 0.5f);
    const float Yf = floorf(posy - 0.5f);
    const float fx = posx - (Xf + 0.5f);
    const float fy = posy - (Yf + 0.5f);

    const float fx2 = fx * fx, fx3 = fx2 * fx;
    const float w0x = -0.5f * fx3 + fx2 - 0.5f * fx;
    const float w1x =  1.5f * fx3 - 2.5f * fx2 + 1.0f;
    const float w2x = -1.5f * fx3 + 2.0f * fx2 + 0.5f * fx;
    const float w3x =  0.5f * fx3 - 0.5f * fx2;
    const float w12x = w1x + w2x;
    const float bxr  = w2x / w12x;

    const float fy2 = fy * fy, fy3 = fy2 * fy;
    const float w0y = -0.5f * fy3 + fy2 - 0.5f * fy;
    const float w1y =  1.5f * fy3 - 2.5f * fy2 + 1.0f;
    const float w2y = -1.5f * fy3 + 2.0f * fy2 + 0.5f * fy;
    const float w3y =  0.5f * fy3 - 0.5f * fy2;
    const float w12y = w1y + w2y;
    const float byr  = w2y / w12y;

    const int X = (int)Xf;
    const int Y = (int)Yf;

    const float vxm1 = ((unsigned)(X - 1) < (unsigned)Wn) ? 1.0f : 0.0f;
    const float vx0  = ((unsigned)(X    ) < (unsigned)Wn) ? 1.0f : 0.0f;
    const float vx1  = ((unsigned)(X + 1) < (unsigned)Wn) ? 1.0f : 0.0f;
    const float vx2  = ((unsigned)(X + 2) < (unsigned)Wn) ? 1.0f : 0.0f;
    const float vym1 = ((unsigned)(Y - 1) < (unsigned)Hn) ? 1.0f : 0.0f;
    const float vy0  = ((unsigned)(Y    ) < (unsigned)Hn) ? 1.0f : 0.0f;
    const float vy1  = ((unsigned)(Y + 1) < (unsigned)Hn) ? 1.0f : 0.0f;
    const float vy2  = ((unsigned)(Y + 2) < (unsigned)Hn) ? 1.0f : 0.0f;

    const int cxm1 = min(max(X - 1, 0), Wn - 1);
    const int cx0  = min(max(X,     0), Wn - 1);
    const int cx1  = min(max(X + 1, 0), Wn - 1);
    const int cx2  = min(max(X + 2, 0), Wn - 1);
    const int rym1 = min(max(Y - 1, 0), Hn - 1) * Wn;
    const int ry0  = min(max(Y,     0), Hn - 1) * Wn;
    const int ry1  = min(max(Y + 1, 0), Hn - 1) * Wn;
    const int ry2  = min(max(Y + 2, 0), Hn - 1) * Wn;

    const float k1 = w12x * w0y;
    const float k2 = w0x * w12y;
    const float k3 = w3x * w12y;
    const float k4 = w12x * w3y;
    const float k5 = w12x * w12y;
    const float inv_denom = 1.0f / (k1 + k2 + k3 + k4 + k5);

    const float wxl = 1.0f - bxr, wxh = bxr;
    const float wyl = 1.0f - byr, wyh = byr;

    const float wA = k1 * wxl * (vym1 * vx0);
    const float wB = k1 * wxh * (vym1 * vx1);
    const float wC = k2 * wyl * (vxm1 * vy0);
    const float wD = k2 * wyh * (vxm1 * vy1);
    const float wE = k3 * wyl * (vx2 * vy0);
    const float wF = k3 * wyh * (vx2 * vy1);
    const float wG = k4 * wxl * (vy2 * vx0);
    const float wH = k4 * wxh * (vy2 * vx1);
    const float wI = k5 * wxl * wyl * (vx0 * vy0);
    const float wJ = k5 * wxh * wyl * (vx1 * vy0);
    const float wK = k5 * wxl * wyh * (vx0 * vy1);
    const float wL = k5 * wxh * wyh * (vx1 * vy1);

    const int oA = rym1 + cx0,  oB = rym1 + cx1;
    const int oC = ry0  + cxm1, oD = ry1  + cxm1;
    const int oE = ry0  + cx2,  oF = ry1  + cx2;
    const int oG = ry2  + cx0,  oH = ry2  + cx1;
    const int oI = ry0  + cx0,  oJ = ry0  + cx1;
    const int oK = ry1  + cx0,  oL = ry1  + cx1;

    float rep[3];

    if constexpr (PACKED) {
        const unsigned int* __restrict__ pp = packed + (size_t)b * HW;
        float accR = 0.0f, accG = 0.0f, accB = 0.0f;
#define TAA_TAP(w_, o_) { const unsigned t = pp[o_];                        \
        accR = fmaf(w_, (float)(t >> 21),          accR);                   \
        accG = fmaf(w_, (float)((t >> 10) & 2047u), accG);                  \
        accB = fmaf(w_, (float)(t & 1023u),        accB); }
        TAA_TAP(wA, oA) TAA_TAP(wB, oB) TAA_TAP(wC, oC) TAA_TAP(wD, oD)
        TAA_TAP(wE, oE) TAA_TAP(wF, oF) TAA_TAP(wG, oG) TAA_TAP(wH, oH)
        TAA_TAP(wI, oI) TAA_TAP(wJ, oJ) TAA_TAP(wK, oK) TAA_TAP(wL, oL)
#undef TAA_TAP
        rep[0] = accR * (kInv2047 * inv_denom);
        rep[1] = accG * (kInv2047 * inv_denom);
        rep[2] = accB * (kInv1023 * inv_denom);
    } else {
        #pragma unroll
        for (int c = 0; c < Cn; ++c) {
            const float* __restrict__ hp = hist + (size_t)(b * Cn + c) * HW;
            float acc = wA * hp[oA];
            acc = fmaf(wB, hp[oB], acc);
            acc = fmaf(wC, hp[oC], acc);
            acc = fmaf(wD, hp[oD], acc);
            acc = fmaf(wE, hp[oE], acc);
            acc = fmaf(wF, hp[oF], acc);
            acc = fmaf(wG, hp[oG], acc);
            acc = fmaf(wH, hp[oH], acc);
            acc = fmaf(wI, hp[oI], acc);
            acc = fmaf(wJ, hp[oJ], acc);
            acc = fmaf(wK, hp[oK], acc);
            acc = fmaf(wL, hp[oL], acc);
            rep[c] = acc * inv_denom;
        }
    }

    const int pym = max(py - 1, 0) * Wn;
    const int py0 = py * Wn;
    const int pyp = min(py + 1, Hn - 1) * Wn;
    const int pxm = max(px - 1, 0);
    const int pxp = min(px + 1, Wn - 1);

    #pragma unroll
    for (int c = 0; c < Cn; ++c) {
        const size_t plane = (size_t)(b * Cn + c) * HW;
        const float* __restrict__ xp = xin + plane;

        const float r0a = xp[pym + pxm], r0b = xp[pym + px], r0c = xp[pym + pxp];
        const float r1a = xp[py0 + pxm], r1b = xp[py0 + px], r1c = xp[py0 + pxp];
        const float r2a = xp[pyp + pxm], r2b = xp[pyp + px], r2c = xp[pyp + pxp];

        const float mx = fmaxf(fmaxf(fmaxf(r0a, r0b), fmaxf(r0c, r1a)),
                               fmaxf(fmaxf(r1b, r1c), fmaxf(fmaxf(r2a, r2b), r2c)));
        const float mn = fminf(fminf(fminf(r0a, r0b), fminf(r0c, r1a)),
                               fminf(fminf(r1b, r1c), fminf(fminf(r2a, r2b), r2c)));

        float rv = fminf(fmaxf(rep[c], 0.0f), 1.0f);  // clip(rgb/denom, 0, 1)
        rv = fminf(fmaxf(rv, mn), mx);                // neighborhood clamp
        __builtin_nontemporal_store(kAlpha * r1b + (1.0f - kAlpha) * rv,
                                    &out[plane + p]);
    }
}

} // namespace

extern "C" void kernel_launch(void* const* d_in, const int* in_sizes, int n_in,
                              void* d_out, int out_size, void* d_ws, size_t ws_size,
                              hipStream_t stream) {
    const float* x    = (const float*)d_in[0];
    const v2f*   mv   = (const v2f*)d_in[1];
    const float* hist = (const float*)d_in[2];
    float* outp = (float*)d_out;

    const int main_blocks = (Wn / 128) * Hn * Bn;   // 64800
    const size_t packed_bytes = (size_t)Bn * HW * 4;

    if (ws_size >= packed_bytes) {
        unsigned int* packed = (unsigned int*)d_ws;
        pack_kernel<<<(Bn * HW) / 256, 256, 0, stream>>>(hist, packed);
        taa_main<true><<<main_blocks, 128, 0, stream>>>(x, mv, hist, packed, outp);
    } else {
        taa_main<false><<<main_blocks, 128, 0, stream>>>(x, mv, hist, nullptr, outp);
    }
}

// Round 3
// 528.392 us; speedup vs baseline: 3.1999x; 1.1918x over previous
//
#include <hip/hip_runtime.h>

namespace {

constexpr int Bn = 4, Cn = 3, Hn = 1080, Wn = 1920;
constexpr int HW = Hn * Wn;
constexpr int Wt = Wn / 4;   // 480 tile-cols
constexpr int Ht = Hn / 4;   // 270 tile-rows
constexpr float kAlpha = 0.1f;
constexpr float kInv2047 = 1.0f / 2047.0f;
constexpr float kInv1023 = 1.0f / 1023.0f;

typedef float v2f __attribute__((ext_vector_type(2)));
typedef float v4f __attribute__((ext_vector_type(4)));
typedef unsigned int v4u __attribute__((ext_vector_type(4)));

// ---- repack planar RGB float -> R11G11B10 dwords in 4x4-texel tiles ----
// One tile = 64B = one cache line. Address(x,y) =
//   ((y>>2)*Wt + (x>>2))*16 + (y&3)*4 + (x&3)   (in dwords, per batch)
// Block = 32 tiles: lane l handles tile-col txg*32+(l&31), row 4*ty+(l>>5);
// reads are contiguous float4 streams, writes are complete 64B lines.
__global__ __launch_bounds__(128)
void pack_tiled(const float* __restrict__ hist, unsigned int* __restrict__ packed)
{
    const int bid = blockIdx.x;            // Bn * Ht * 15
    const int b   = bid / (Ht * 15);
    const int r2  = bid - b * (Ht * 15);
    const int ty  = r2 / 15;
    const int txg = r2 - ty * 15;
    const int l   = threadIdx.x;
    const int tx  = txg * 32 + (l & 31);
    const int y   = ty * 4 + (l >> 5);
    const int x0  = tx * 4;

    const float* base = hist + (size_t)b * Cn * HW + (size_t)y * Wn + x0;
    const v4f r  = *(const v4f*)(base);
    const v4f g  = *(const v4f*)(base + HW);
    const v4f bl = *(const v4f*)(base + 2 * HW);

    v4u t;
    #pragma unroll
    for (int i = 0; i < 4; ++i) {
        const unsigned R  = (unsigned)(fminf(fmaxf(r[i],  0.0f), 1.0f) * 2047.0f + 0.5f);
        const unsigned G  = (unsigned)(fminf(fmaxf(g[i],  0.0f), 1.0f) * 2047.0f + 0.5f);
        const unsigned Bq = (unsigned)(fminf(fmaxf(bl[i], 0.0f), 1.0f) * 1023.0f + 0.5f);
        t[i] = (R << 21) | (G << 10) | Bq;
    }
    unsigned int* dst = packed + (size_t)b * HW + ((size_t)ty * Wt + tx) * 16 + (y & 3) * 4;
    *(v4u*)dst = t;
}

__device__ inline unsigned sel4(unsigned a, unsigned b, unsigned c, unsigned d, int s)
{
    const unsigned lo = (s & 1) ? b : a;
    const unsigned hi = (s & 1) ? d : c;
    return (s & 2) ? hi : lo;
}

// ---- main TAA kernel ----
template <bool PACKED>
__global__ __launch_bounds__(128)
void taa_main(const float* __restrict__ xin,
              const v2f* __restrict__ mv,
              const float* __restrict__ hist,
              const unsigned int* __restrict__ packed,
              float* __restrict__ out)
{
    // batch = bid & 3: round-robin block->XCD (i%8) pins batch b to XCDs {b,b+4},
    // so each XCD's 4MB L2 holds one batch's ~2MB gather working set.
    const int bid = blockIdx.x;
    const int b   = bid & 3;
    const int rr  = bid >> 2;
    const int py  = rr / 15;
    const int px  = (rr - py * 15) * 128 + threadIdx.x;
    const int p   = py * Wn + px;

    const v2f g = __builtin_nontemporal_load(&mv[(size_t)b * HW + p]);

    const float posx = (g.x + 1.0f) * 0.5f * (float)Wn;
    const float posy = (g.y + 1.0f) * 0.5f * (float)Hn;
    const float Xf = floorf(posx - 0.5f);
    const float Yf = floorf(posy - 0.5f);
    const float fx = posx - (Xf + 0.5f);
    const float fy = posy - (Yf + 0.5f);

    const float fx2 = fx * fx, fx3 = fx2 * fx;
    const float w0x = -0.5f * fx3 + fx2 - 0.5f * fx;
    const float w1x =  1.5f * fx3 - 2.5f * fx2 + 1.0f;
    const float w2x = -1.5f * fx3 + 2.0f * fx2 + 0.5f * fx;
    const float w3x =  0.5f * fx3 - 0.5f * fx2;
    const float w12x = w1x + w2x;
    const float bxr  = w2x / w12x;

    const float fy2 = fy * fy, fy3 = fy2 * fy;
    const float w0y = -0.5f * fy3 + fy2 - 0.5f * fy;
    const float w1y =  1.5f * fy3 - 2.5f * fy2 + 1.0f;
    const float w2y = -1.5f * fy3 + 2.0f * fy2 + 0.5f * fy;
    const float w3y =  0.5f * fy3 - 0.5f * fy2;
    const float w12y = w1y + w2y;
    const float byr  = w2y / w12y;

    const int X = (int)Xf;
    const int Y = (int)Yf;

    // zero-padding validity
    const float vxm1 = ((unsigned)(X - 1) < (unsigned)Wn) ? 1.0f : 0.0f;
    const float vx0  = ((unsigned)(X    ) < (unsigned)Wn) ? 1.0f : 0.0f;
    const float vx1  = ((unsigned)(X + 1) < (unsigned)Wn) ? 1.0f : 0.0f;
    const float vx2  = ((unsigned)(X + 2) < (unsigned)Wn) ? 1.0f : 0.0f;
    const float vym1 = ((unsigned)(Y - 1) < (unsigned)Hn) ? 1.0f : 0.0f;
    const float vy0  = ((unsigned)(Y    ) < (unsigned)Hn) ? 1.0f : 0.0f;
    const float vy1  = ((unsigned)(Y + 1) < (unsigned)Hn) ? 1.0f : 0.0f;
    const float vy2  = ((unsigned)(Y + 2) < (unsigned)Hn) ? 1.0f : 0.0f;

    const float k1 = w12x * w0y;
    const float k2 = w0x * w12y;
    const float k3 = w3x * w12y;
    const float k4 = w12x * w3y;
    const float k5 = w12x * w12y;
    const float inv_denom = 1.0f / (k1 + k2 + k3 + k4 + k5);

    const float wxl = 1.0f - bxr, wxh = bxr;
    const float wyl = 1.0f - byr, wyh = byr;

    // per-texel folded weights (tap x bilinear x validity)
    const float wA = k1 * wxl * (vym1 * vx0);   // (Y-1, X)
    const float wB = k1 * wxh * (vym1 * vx1);   // (Y-1, X+1)
    const float wC = k2 * wyl * (vxm1 * vy0);   // (Y,   X-1)
    const float wD = k2 * wyh * (vxm1 * vy1);   // (Y+1, X-1)
    const float wE = k3 * wyl * (vx2 * vy0);    // (Y,   X+2)
    const float wF = k3 * wyh * (vx2 * vy1);    // (Y+1, X+2)
    const float wG = k4 * wxl * (vy2 * vx0);    // (Y+2, X)
    const float wH = k4 * wxh * (vy2 * vx1);    // (Y+2, X+1)
    const float wI = k5 * wxl * wyl * (vx0 * vy0);  // (Y,   X)
    const float wJ = k5 * wxh * wyl * (vx1 * vy0);  // (Y,   X+1)
    const float wK = k5 * wxl * wyh * (vx0 * vy1);  // (Y+1, X)
    const float wL = k5 * wxh * wyh * (vx1 * vy1);  // (Y+1, X+1)

    float rep[3];

    if constexpr (PACKED) {
        const unsigned int* __restrict__ pp = packed + (size_t)b * HW;

        const int rYm = min(max(Y - 1, 0), Hn - 1);
        const int rY0 = min(max(Y,     0), Hn - 1);
        const int rY1 = min(max(Y + 1, 0), Hn - 1);
        const int rY2 = min(max(Y + 2, 0), Hn - 1);
        const int cX  = min(max(X,     0), Wn - 1);
        const int cX1 = min(max(X + 1, 0), Wn - 1);
        const int tx0 = min(max((X - 1) >> 2, 0), Wt - 1);
        const int tx1 = min(max((X + 2) >> 2, 0), Wt - 1);
        const int s1  = (X - 1) & 3;

        // tile-row bases (16B-aligned dwordx4)
        #define ROWBASE(rc, tx) ((((rc) >> 2) * Wt + (tx)) * 16 + ((rc) & 3) * 4)
        #define TEXADDR(rc, x)  ((((rc) >> 2) * Wt + ((x) >> 2)) * 16 + ((rc) & 3) * 4 + ((x) & 3))

        const v4u A0 = *(const v4u*)(pp + ROWBASE(rY0, tx0));
        const v4u B0 = *(const v4u*)(pp + ROWBASE(rY0, tx1));
        const v4u A1 = *(const v4u*)(pp + ROWBASE(rY1, tx0));
        const v4u B1 = *(const v4u*)(pp + ROWBASE(rY1, tx1));
        const unsigned tA = pp[TEXADDR(rYm, cX)];
        const unsigned tB = pp[TEXADDR(rYm, cX1)];
        const unsigned tG = pp[TEXADDR(rY2, cX)];
        const unsigned tH = pp[TEXADDR(rY2, cX1)];
        #undef ROWBASE
        #undef TEXADDR

        // extract cols X-1..X+2 from the two loaded tile-rows
        const unsigned tC = sel4(A0.x, A0.y, A0.z, A0.w, s1);
        const unsigned tI = sel4(A0.y, A0.z, A0.w, B0.x, s1);
        const unsigned tJ = sel4(A0.z, A0.w, B0.x, B0.y, s1);
        const unsigned tE = sel4(A0.w, B0.x, B0.y, B0.z, s1);
        const unsigned tD = sel4(A1.x, A1.y, A1.z, A1.w, s1);
        const unsigned tK = sel4(A1.y, A1.z, A1.w, B1.x, s1);
        const unsigned tL = sel4(A1.z, A1.w, B1.x, B1.y, s1);
        const unsigned tF = sel4(A1.w, B1.x, B1.y, B1.z, s1);

        float accR = 0.0f, accG = 0.0f, accB = 0.0f;
#define TAA_TAP(w_, t_) {                                                   \
        accR = fmaf(w_, (float)((t_) >> 21),           accR);               \
        accG = fmaf(w_, (float)(((t_) >> 10) & 2047u), accG);               \
        accB = fmaf(w_, (float)((t_) & 1023u),         accB); }
        TAA_TAP(wA, tA) TAA_TAP(wB, tB) TAA_TAP(wC, tC) TAA_TAP(wD, tD)
        TAA_TAP(wE, tE) TAA_TAP(wF, tF) TAA_TAP(wG, tG) TAA_TAP(wH, tH)
        TAA_TAP(wI, tI) TAA_TAP(wJ, tJ) TAA_TAP(wK, tK) TAA_TAP(wL, tL)
#undef TAA_TAP
        rep[0] = accR * (kInv2047 * inv_denom);
        rep[1] = accG * (kInv2047 * inv_denom);
        rep[2] = accB * (kInv1023 * inv_denom);
    } else {
        // planar fallback (ws too small)
        const int cxm1 = min(max(X - 1, 0), Wn - 1);
        const int cx0  = min(max(X,     0), Wn - 1);
        const int cx1  = min(max(X + 1, 0), Wn - 1);
        const int cx2  = min(max(X + 2, 0), Wn - 1);
        const int rym1 = min(max(Y - 1, 0), Hn - 1) * Wn;
        const int ry0  = min(max(Y,     0), Hn - 1) * Wn;
        const int ry1  = min(max(Y + 1, 0), Hn - 1) * Wn;
        const int ry2  = min(max(Y + 2, 0), Hn - 1) * Wn;
        #pragma unroll
        for (int c = 0; c < Cn; ++c) {
            const float* __restrict__ hp = hist + (size_t)(b * Cn + c) * HW;
            float acc = wA * hp[rym1 + cx0];
            acc = fmaf(wB, hp[rym1 + cx1], acc);
            acc = fmaf(wC, hp[ry0 + cxm1], acc);
            acc = fmaf(wD, hp[ry1 + cxm1], acc);
            acc = fmaf(wE, hp[ry0 + cx2], acc);
            acc = fmaf(wF, hp[ry1 + cx2], acc);
            acc = fmaf(wG, hp[ry2 + cx0], acc);
            acc = fmaf(wH, hp[ry2 + cx1], acc);
            acc = fmaf(wI, hp[ry0 + cx0], acc);
            acc = fmaf(wJ, hp[ry0 + cx1], acc);
            acc = fmaf(wK, hp[ry1 + cx0], acc);
            acc = fmaf(wL, hp[ry1 + cx1], acc);
            rep[c] = acc * inv_denom;
        }
    }

    const int pym = max(py - 1, 0) * Wn;
    const int py0 = py * Wn;
    const int pyp = min(py + 1, Hn - 1) * Wn;
    const int pxm = max(px - 1, 0);
    const int pxp = min(px + 1, Wn - 1);

    #pragma unroll
    for (int c = 0; c < Cn; ++c) {
        const size_t plane = (size_t)(b * Cn + c) * HW;
        const float* __restrict__ xp = xin + plane;

        const float r0a = xp[pym + pxm], r0b = xp[pym + px], r0c = xp[pym + pxp];
        const float r1a = xp[py0 + pxm], r1b = xp[py0 + px], r1c = xp[py0 + pxp];
        const float r2a = xp[pyp + pxm], r2b = xp[pyp + px], r2c = xp[pyp + pxp];

        const float mx = fmaxf(fmaxf(fmaxf(r0a, r0b), fmaxf(r0c, r1a)),
                               fmaxf(fmaxf(r1b, r1c), fmaxf(fmaxf(r2a, r2b), r2c)));
        const float mn = fminf(fminf(fminf(r0a, r0b), fminf(r0c, r1a)),
                               fminf(fminf(r1b, r1c), fminf(fminf(r2a, r2b), r2c)));

        float rv = fminf(fmaxf(rep[c], 0.0f), 1.0f);
        rv = fminf(fmaxf(rv, mn), mx);
        __builtin_nontemporal_store(kAlpha * r1b + (1.0f - kAlpha) * rv,
                                    &out[plane + p]);
    }
}

} // namespace

extern "C" void kernel_launch(void* const* d_in, const int* in_sizes, int n_in,
                              void* d_out, int out_size, void* d_ws, size_t ws_size,
                              hipStream_t stream) {
    const float* x    = (const float*)d_in[0];
    const v2f*   mv   = (const v2f*)d_in[1];
    const float* hist = (const float*)d_in[2];
    float* outp = (float*)d_out;

    const int main_blocks = (Wn / 128) * Hn * Bn;   // 64800
    const size_t packed_bytes = (size_t)Bn * HW * 4;

    if (ws_size >= packed_bytes) {
        unsigned int* packed = (unsigned int*)d_ws;
        pack_tiled<<<Bn * Ht * 15, 128, 0, stream>>>(hist, packed);
        taa_main<true><<<main_blocks, 128, 0, stream>>>(x, mv, hist, packed, outp);
    } else {
        taa_main<false><<<main_blocks, 128, 0, stream>>>(x, mv, hist, nullptr, outp);
    }
}

// Round 4
// 468.272 us; speedup vs baseline: 3.6108x; 1.1284x over previous
//
#include <hip/hip_runtime.h>

namespace {

constexpr int Bn = 4, Cn = 3, Hn = 1080, Wn = 1920;
constexpr int HW = Hn * Wn;
constexpr int Wt = Wn / 4;   // 480 tile-cols
constexpr int Ht = Hn / 4;   // 270 tile-rows
constexpr float kAlpha = 0.1f;
constexpr float kInv2047 = 1.0f / 2047.0f;
constexpr float kInv1023 = 1.0f / 1023.0f;

typedef float v2f __attribute__((ext_vector_type(2)));
typedef float v4f __attribute__((ext_vector_type(4)));
typedef unsigned int v4u __attribute__((ext_vector_type(4)));

// ---- repack planar RGB float -> R11G11B10 dwords in 4x4-texel tiles ----
// One tile = 64B = one cache line. Dword address(x,y) per batch =
//   ((y>>2)*Wt + (x>>2))*16 + (y&3)*4 + (x&3)
__global__ __launch_bounds__(128)
void pack_tiled(const float* __restrict__ hist, unsigned int* __restrict__ packed)
{
    const int bid = blockIdx.x;            // Bn * Ht * 15
    const int b   = bid / (Ht * 15);
    const int r2  = bid - b * (Ht * 15);
    const int ty  = r2 / 15;
    const int txg = r2 - ty * 15;
    const int l   = threadIdx.x;
    const int tx  = txg * 32 + (l & 31);
    const int y   = ty * 4 + (l >> 5);
    const int x0  = tx * 4;

    const float* base = hist + (size_t)b * Cn * HW + (size_t)y * Wn + x0;
    const v4f r  = *(const v4f*)(base);
    const v4f g  = *(const v4f*)(base + HW);
    const v4f bl = *(const v4f*)(base + 2 * HW);

    v4u t;
    #pragma unroll
    for (int i = 0; i < 4; ++i) {
        const unsigned R  = (unsigned)(fminf(fmaxf(r[i],  0.0f), 1.0f) * 2047.0f + 0.5f);
        const unsigned G  = (unsigned)(fminf(fmaxf(g[i],  0.0f), 1.0f) * 2047.0f + 0.5f);
        const unsigned Bq = (unsigned)(fminf(fmaxf(bl[i], 0.0f), 1.0f) * 1023.0f + 0.5f);
        t[i] = (R << 21) | (G << 10) | Bq;
    }
    unsigned int* dst = packed + (size_t)b * HW + ((size_t)ty * Wt + tx) * 16 + (y & 3) * 4;
    *(v4u*)dst = t;
}

__device__ inline unsigned sel4(unsigned a, unsigned b, unsigned c, unsigned d, int s)
{
    const unsigned lo = (s & 1) ? b : a;
    const unsigned hi = (s & 1) ? d : c;
    return (s & 2) ? hi : lo;
}

// ---- main TAA kernel ----
template <bool PACKED>
__global__ __launch_bounds__(128)
void taa_main(const float* __restrict__ xin,
              const v2f* __restrict__ mv,
              const float* __restrict__ hist,
              const unsigned int* __restrict__ packed,
              float* __restrict__ out)
{
    // batch = bid & 3: round-robin block->XCD (i%8) pins batch b to XCDs {b,b+4},
    // so each XCD's 4MB L2 holds one batch's ~2MB gather working set.
    const int bid = blockIdx.x;
    const int b   = bid & 3;
    const int rr  = bid >> 2;
    const int py  = rr / 15;
    const int px  = (rr - py * 15) * 128 + threadIdx.x;
    const int p   = py * Wn + px;

    const v2f g = __builtin_nontemporal_load(&mv[(size_t)b * HW + p]);

    const float posx = (g.x + 1.0f) * 0.5f * (float)Wn;
    const float posy = (g.y + 1.0f) * 0.5f * (float)Hn;
    const float Xf = floorf(posx - 0.5f);
    const float Yf = floorf(posy - 0.5f);
    const float fx = posx - (Xf + 0.5f);
    const float fy = posy - (Yf + 0.5f);

    const float fx2 = fx * fx, fx3 = fx2 * fx;
    const float w0x = -0.5f * fx3 + fx2 - 0.5f * fx;
    const float w1x =  1.5f * fx3 - 2.5f * fx2 + 1.0f;
    const float w2x = -1.5f * fx3 + 2.0f * fx2 + 0.5f * fx;
    const float w3x =  0.5f * fx3 - 0.5f * fx2;
    const float w12x = w1x + w2x;
    const float bxr  = w2x / w12x;

    const float fy2 = fy * fy, fy3 = fy2 * fy;
    const float w0y = -0.5f * fy3 + fy2 - 0.5f * fy;
    const float w1y =  1.5f * fy3 - 2.5f * fy2 + 1.0f;
    const float w2y = -1.5f * fy3 + 2.0f * fy2 + 0.5f * fy;
    const float w3y =  0.5f * fy3 - 0.5f * fy2;
    const float w12y = w1y + w2y;
    const float byr  = w2y / w12y;

    const int X = (int)Xf;
    const int Y = (int)Yf;

    // zero-padding validity
    const float vxm1 = ((unsigned)(X - 1) < (unsigned)Wn) ? 1.0f : 0.0f;
    const float vx0  = ((unsigned)(X    ) < (unsigned)Wn) ? 1.0f : 0.0f;
    const float vx1  = ((unsigned)(X + 1) < (unsigned)Wn) ? 1.0f : 0.0f;
    const float vx2  = ((unsigned)(X + 2) < (unsigned)Wn) ? 1.0f : 0.0f;
    const float vym1 = ((unsigned)(Y - 1) < (unsigned)Hn) ? 1.0f : 0.0f;
    const float vy0  = ((unsigned)(Y    ) < (unsigned)Hn) ? 1.0f : 0.0f;
    const float vy1  = ((unsigned)(Y + 1) < (unsigned)Hn) ? 1.0f : 0.0f;
    const float vy2  = ((unsigned)(Y + 2) < (unsigned)Hn) ? 1.0f : 0.0f;

    const float k1 = w12x * w0y;
    const float k2 = w0x * w12y;
    const float k3 = w3x * w12y;
    const float k4 = w12x * w3y;
    const float k5 = w12x * w12y;
    const float inv_denom = 1.0f / (k1 + k2 + k3 + k4 + k5);

    const float wxl = 1.0f - bxr, wxh = bxr;
    const float wyl = 1.0f - byr, wyh = byr;

    // per-texel folded weights (tap x bilinear x validity)
    const float wA = k1 * wxl * (vym1 * vx0);   // (Y-1, X)
    const float wB = k1 * wxh * (vym1 * vx1);   // (Y-1, X+1)
    const float wC = k2 * wyl * (vxm1 * vy0);   // (Y,   X-1)
    const float wD = k2 * wyh * (vxm1 * vy1);   // (Y+1, X-1)
    const float wE = k3 * wyl * (vx2 * vy0);    // (Y,   X+2)
    const float wF = k3 * wyh * (vx2 * vy1);    // (Y+1, X+2)
    const float wG = k4 * wxl * (vy2 * vx0);    // (Y+2, X)
    const float wH = k4 * wxh * (vy2 * vx1);    // (Y+2, X+1)
    const float wI = k5 * wxl * wyl * (vx0 * vy0);  // (Y,   X)
    const float wJ = k5 * wxh * wyl * (vx1 * vy0);  // (Y,   X+1)
    const float wK = k5 * wxl * wyh * (vx0 * vy1);  // (Y+1, X)
    const float wL = k5 * wxh * wyh * (vx1 * vy1);  // (Y+1, X+1)

    float rep[3];

    if constexpr (PACKED) {
        const unsigned int* __restrict__ pp = packed + (size_t)b * HW;

        const int rYm = min(max(Y - 1, 0), Hn - 1);
        const int rY0 = min(max(Y,     0), Hn - 1);
        const int rY1 = min(max(Y + 1, 0), Hn - 1);
        const int rY2 = min(max(Y + 2, 0), Hn - 1);
        const int cX  = min(max(X,     0), Wn - 1);
        const int cX1 = min(max(X + 1, 0), Wn - 1);
        const int tx0 = min(max((X - 1) >> 2, 0), Wt - 1);
        const int tx1 = min(max((X + 2) >> 2, 0), Wt - 1);
        const int s1  = (X - 1) & 3;

        #define ROWBASE(rc, tx) ((((rc) >> 2) * Wt + (tx)) * 16 + ((rc) & 3) * 4)

        // rows Y, Y+1: first tile-row always; second only if span crosses tiles
        const v4u A0 = *(const v4u*)(pp + ROWBASE(rY0, tx0));
        const v4u A1 = *(const v4u*)(pp + ROWBASE(rY1, tx0));
        v4u B0 = {0, 0, 0, 0}, B1 = {0, 0, 0, 0};
        if (s1 != 0) {                       // 75% of lanes
            B0 = *(const v4u*)(pp + ROWBASE(rY0, tx1));
            B1 = *(const v4u*)(pp + ROWBASE(rY1, tx1));
        }

        // rows Y-1, Y+2: full tile-row containing col X; second tile only if
        // col X+1 spills into the next tile (25% of lanes)
        const int txA = cX >> 2;
        const int sA  = cX & 3;
        const int sB  = cX1 & 3;
        const bool nb = (cX1 >> 2) != txA;
        const v4u Tm = *(const v4u*)(pp + ROWBASE(rYm, txA));
        const v4u T2 = *(const v4u*)(pp + ROWBASE(rY2, txA));
        unsigned um = 0, u2 = 0;
        if (nb) {
            um = pp[ROWBASE(rYm, txA + 1)];
            u2 = pp[ROWBASE(rY2, txA + 1)];
        }
        #undef ROWBASE

        const unsigned tA = sel4(Tm.x, Tm.y, Tm.z, Tm.w, sA);
        const unsigned tG = sel4(T2.x, T2.y, T2.z, T2.w, sA);
        const unsigned tB = nb ? um : sel4(Tm.x, Tm.y, Tm.z, Tm.w, sB);
        const unsigned tH = nb ? u2 : sel4(T2.x, T2.y, T2.z, T2.w, sB);

        const unsigned tC = sel4(A0.x, A0.y, A0.z, A0.w, s1);
        const unsigned tI = sel4(A0.y, A0.z, A0.w, B0.x, s1);
        const unsigned tJ = sel4(A0.z, A0.w, B0.x, B0.y, s1);
        const unsigned tE = sel4(A0.w, B0.x, B0.y, B0.z, s1);
        const unsigned tD = sel4(A1.x, A1.y, A1.z, A1.w, s1);
        const unsigned tK = sel4(A1.y, A1.z, A1.w, B1.x, s1);
        const unsigned tL = sel4(A1.z, A1.w, B1.x, B1.y, s1);
        const unsigned tF = sel4(A1.w, B1.x, B1.y, B1.z, s1);

        float accR = 0.0f, accG = 0.0f, accB = 0.0f;
#define TAA_TAP(w_, t_) {                                                   \
        accR = fmaf(w_, (float)((t_) >> 21),           accR);               \
        accG = fmaf(w_, (float)(((t_) >> 10) & 2047u), accG);               \
        accB = fmaf(w_, (float)((t_) & 1023u),         accB); }
        TAA_TAP(wA, tA) TAA_TAP(wB, tB) TAA_TAP(wC, tC) TAA_TAP(wD, tD)
        TAA_TAP(wE, tE) TAA_TAP(wF, tF) TAA_TAP(wG, tG) TAA_TAP(wH, tH)
        TAA_TAP(wI, tI) TAA_TAP(wJ, tJ) TAA_TAP(wK, tK) TAA_TAP(wL, tL)
#undef TAA_TAP
        rep[0] = accR * (kInv2047 * inv_denom);
        rep[1] = accG * (kInv2047 * inv_denom);
        rep[2] = accB * (kInv1023 * inv_denom);
    } else {
        const int cxm1 = min(max(X - 1, 0), Wn - 1);
        const int cx0  = min(max(X,     0), Wn - 1);
        const int cx1  = min(max(X + 1, 0), Wn - 1);
        const int cx2  = min(max(X + 2, 0), Wn - 1);
        const int rym1 = min(max(Y - 1, 0), Hn - 1) * Wn;
        const int ry0  = min(max(Y,     0), Hn - 1) * Wn;
        const int ry1  = min(max(Y + 1, 0), Hn - 1) * Wn;
        const int ry2  = min(max(Y + 2, 0), Hn - 1) * Wn;
        #pragma unroll
        for (int c = 0; c < Cn; ++c) {
            const float* __restrict__ hp = hist + (size_t)(b * Cn + c) * HW;
            float acc = wA * hp[rym1 + cx0];
            acc = fmaf(wB, hp[rym1 + cx1], acc);
            acc = fmaf(wC, hp[ry0 + cxm1], acc);
            acc = fmaf(wD, hp[ry1 + cxm1], acc);
            acc = fmaf(wE, hp[ry0 + cx2], acc);
            acc = fmaf(wF, hp[ry1 + cx2], acc);
            acc = fmaf(wG, hp[ry2 + cx0], acc);
            acc = fmaf(wH, hp[ry2 + cx1], acc);
            acc = fmaf(wI, hp[ry0 + cx0], acc);
            acc = fmaf(wJ, hp[ry0 + cx1], acc);
            acc = fmaf(wK, hp[ry1 + cx0], acc);
            acc = fmaf(wL, hp[ry1 + cx1], acc);
            rep[c] = acc * inv_denom;
        }
    }

    // ---- 3x3 neighborhood min/max: center-column loads + wave shuffles ----
    const int pym = max(py - 1, 0) * Wn;
    const int py0 = py * Wn;
    const int pyp = min(py + 1, Hn - 1) * Wn;
    const int pxm = max(px - 1, 0);
    const int pxp = min(px + 1, Wn - 1);
    const int lane = threadIdx.x & 63;

    float ctr[3], cmx[3], cmn[3];
    #pragma unroll
    for (int c = 0; c < Cn; ++c) {
        const float* __restrict__ xp = xin + (size_t)(b * Cn + c) * HW;
        const float c0 = xp[pym + px];
        const float c1 = xp[py0 + px];
        const float c2 = xp[pyp + px];
        ctr[c] = c1;
        cmx[c] = fmaxf(fmaxf(c0, c1), c2);
        cmn[c] = fminf(fminf(c0, c1), c2);
    }

    float lmx[3], rmx[3], lmn[3], rmn[3];
    #pragma unroll
    for (int c = 0; c < Cn; ++c) {
        lmx[c] = __shfl_up(cmx[c], 1);
        rmx[c] = __shfl_down(cmx[c], 1);
        lmn[c] = __shfl_up(cmn[c], 1);
        rmn[c] = __shfl_down(cmn[c], 1);
    }

    // wave-edge lanes fetch the neighbor column directly (2 active lanes)
    if (lane == 0 || lane == 63) {
        const int ex = (lane == 0) ? pxm : pxp;
        #pragma unroll
        for (int c = 0; c < Cn; ++c) {
            const float* __restrict__ xp = xin + (size_t)(b * Cn + c) * HW;
            const float e0 = xp[pym + ex];
            const float e1 = xp[py0 + ex];
            const float e2 = xp[pyp + ex];
            const float emax = fmaxf(fmaxf(e0, e1), e2);
            const float emin = fminf(fminf(e0, e1), e2);
            if (lane == 0) { lmx[c] = emax; lmn[c] = emin; }
            else           { rmx[c] = emax; rmn[c] = emin; }
        }
    }

    #pragma unroll
    for (int c = 0; c < Cn; ++c) {
        const float mx = fmaxf(fmaxf(lmx[c], cmx[c]), rmx[c]);
        const float mn = fminf(fminf(lmn[c], cmn[c]), rmn[c]);
        float rv = fminf(fmaxf(rep[c], 0.0f), 1.0f);
        rv = fminf(fmaxf(rv, mn), mx);
        __builtin_nontemporal_store(kAlpha * ctr[c] + (1.0f - kAlpha) * rv,
                                    &out[(size_t)(b * Cn + c) * HW + p]);
    }
}

} // namespace

extern "C" void kernel_launch(void* const* d_in, const int* in_sizes, int n_in,
                              void* d_out, int out_size, void* d_ws, size_t ws_size,
                              hipStream_t stream) {
    const float* x    = (const float*)d_in[0];
    const v2f*   mv   = (const v2f*)d_in[1];
    const float* hist = (const float*)d_in[2];
    float* outp = (float*)d_out;

    const int main_blocks = (Wn / 128) * Hn * Bn;   // 64800
    const size_t packed_bytes = (size_t)Bn * HW * 4;

    if (ws_size >= packed_bytes) {
        unsigned int* packed = (unsigned int*)d_ws;
        pack_tiled<<<Bn * Ht * 15, 128, 0, stream>>>(hist, packed);
        taa_main<true><<<main_blocks, 128, 0, stream>>>(x, mv, hist, packed, outp);
    } else {
        taa_main<false><<<main_blocks, 128, 0, stream>>>(x, mv, hist, nullptr, outp);
    }
}

// Round 5
// 441.124 us; speedup vs baseline: 3.8330x; 1.0615x over previous
//
#include <hip/hip_runtime.h>

namespace {

constexpr int Bn = 4, Cn = 3, Hn = 1080, Wn = 1920;
constexpr int HW = Hn * Wn;
constexpr int Wt = Wn / 4;   // 480 tile-cols
constexpr int Ht = Hn / 4;   // 270 tile-rows
constexpr float kAlpha = 0.1f;
constexpr float kInv2047 = 1.0f / 2047.0f;
constexpr float kInv1023 = 1.0f / 1023.0f;

typedef float v2f __attribute__((ext_vector_type(2)));
typedef float v4f __attribute__((ext_vector_type(4)));
typedef unsigned int v4u __attribute__((ext_vector_type(4)));

// ---- repack planar RGB float -> R11G11B10 dwords in 4x4-texel tiles ----
// One tile = 64B = one cache line. Dword address(x,y) per batch =
//   ((y>>2)*Wt + (x>>2))*16 + (y&3)*4 + (x&3)
__global__ __launch_bounds__(128)
void pack_tiled(const float* __restrict__ hist, unsigned int* __restrict__ packed)
{
    const int bid = blockIdx.x;            // Bn * Ht * 15
    const int b   = bid / (Ht * 15);
    const int r2  = bid - b * (Ht * 15);
    const int ty  = r2 / 15;
    const int txg = r2 - ty * 15;
    const int l   = threadIdx.x;
    const int tx  = txg * 32 + (l & 31);
    const int y   = ty * 4 + (l >> 5);
    const int x0  = tx * 4;

    const float* base = hist + (size_t)b * Cn * HW + (size_t)y * Wn + x0;
    const v4f r  = *(const v4f*)(base);
    const v4f g  = *(const v4f*)(base + HW);
    const v4f bl = *(const v4f*)(base + 2 * HW);

    v4u t;
    #pragma unroll
    for (int i = 0; i < 4; ++i) {
        const unsigned R  = (unsigned)(fminf(fmaxf(r[i],  0.0f), 1.0f) * 2047.0f + 0.5f);
        const unsigned G  = (unsigned)(fminf(fmaxf(g[i],  0.0f), 1.0f) * 2047.0f + 0.5f);
        const unsigned Bq = (unsigned)(fminf(fmaxf(bl[i], 0.0f), 1.0f) * 1023.0f + 0.5f);
        t[i] = (R << 21) | (G << 10) | Bq;
    }
    unsigned int* dst = packed + (size_t)b * HW + ((size_t)ty * Wt + tx) * 16 + (y & 3) * 4;
    *(v4u*)dst = t;
}

__device__ inline unsigned sel4(unsigned a, unsigned b, unsigned c, unsigned d, int s)
{
    const unsigned lo = (s & 1) ? b : a;
    const unsigned hi = (s & 1) ? d : c;
    return (s & 2) ? hi : lo;
}

// one pixel's 5-tap bicubic from the tiled packed texture (~6 VMEM requests)
__device__ inline void bicubic_gather(const unsigned int* __restrict__ pp,
                                      float gx, float gy, float rep[3])
{
    const float posx = (gx + 1.0f) * 0.5f * (float)Wn;
    const float posy = (gy + 1.0f) * 0.5f * (float)Hn;
    const float Xf = floorf(posx - 0.5f);
    const float Yf = floorf(posy - 0.5f);
    const float fx = posx - (Xf + 0.5f);
    const float fy = posy - (Yf + 0.5f);

    const float fx2 = fx * fx, fx3 = fx2 * fx;
    const float w0x = -0.5f * fx3 + fx2 - 0.5f * fx;
    const float w1x =  1.5f * fx3 - 2.5f * fx2 + 1.0f;
    const float w2x = -1.5f * fx3 + 2.0f * fx2 + 0.5f * fx;
    const float w3x =  0.5f * fx3 - 0.5f * fx2;
    const float w12x = w1x + w2x;
    const float bxr  = w2x / w12x;

    const float fy2 = fy * fy, fy3 = fy2 * fy;
    const float w0y = -0.5f * fy3 + fy2 - 0.5f * fy;
    const float w1y =  1.5f * fy3 - 2.5f * fy2 + 1.0f;
    const float w2y = -1.5f * fy3 + 2.0f * fy2 + 0.5f * fy;
    const float w3y =  0.5f * fy3 - 0.5f * fy2;
    const float w12y = w1y + w2y;
    const float byr  = w2y / w12y;

    const int X = (int)Xf;
    const int Y = (int)Yf;

    const float vxm1 = ((unsigned)(X - 1) < (unsigned)Wn) ? 1.0f : 0.0f;
    const float vx0  = ((unsigned)(X    ) < (unsigned)Wn) ? 1.0f : 0.0f;
    const float vx1  = ((unsigned)(X + 1) < (unsigned)Wn) ? 1.0f : 0.0f;
    const float vx2  = ((unsigned)(X + 2) < (unsigned)Wn) ? 1.0f : 0.0f;
    const float vym1 = ((unsigned)(Y - 1) < (unsigned)Hn) ? 1.0f : 0.0f;
    const float vy0  = ((unsigned)(Y    ) < (unsigned)Hn) ? 1.0f : 0.0f;
    const float vy1  = ((unsigned)(Y + 1) < (unsigned)Hn) ? 1.0f : 0.0f;
    const float vy2  = ((unsigned)(Y + 2) < (unsigned)Hn) ? 1.0f : 0.0f;

    const float k1 = w12x * w0y;
    const float k2 = w0x * w12y;
    const float k3 = w3x * w12y;
    const float k4 = w12x * w3y;
    const float k5 = w12x * w12y;
    const float inv_denom = 1.0f / (k1 + k2 + k3 + k4 + k5);

    const float wxl = 1.0f - bxr, wxh = bxr;
    const float wyl = 1.0f - byr, wyh = byr;

    const float wA = k1 * wxl * (vym1 * vx0);
    const float wB = k1 * wxh * (vym1 * vx1);
    const float wC = k2 * wyl * (vxm1 * vy0);
    const float wD = k2 * wyh * (vxm1 * vy1);
    const float wE = k3 * wyl * (vx2 * vy0);
    const float wF = k3 * wyh * (vx2 * vy1);
    const float wG = k4 * wxl * (vy2 * vx0);
    const float wH = k4 * wxh * (vy2 * vx1);
    const float wI = k5 * wxl * wyl * (vx0 * vy0);
    const float wJ = k5 * wxh * wyl * (vx1 * vy0);
    const float wK = k5 * wxl * wyh * (vx0 * vy1);
    const float wL = k5 * wxh * wyh * (vx1 * vy1);

    const int rYm = min(max(Y - 1, 0), Hn - 1);
    const int rY0 = min(max(Y,     0), Hn - 1);
    const int rY1 = min(max(Y + 1, 0), Hn - 1);
    const int rY2 = min(max(Y + 2, 0), Hn - 1);
    const int cX  = min(max(X,     0), Wn - 1);
    const int cX1 = min(max(X + 1, 0), Wn - 1);
    const int tx0 = min(max((X - 1) >> 2, 0), Wt - 1);
    const int tx1 = min(max((X + 2) >> 2, 0), Wt - 1);
    const int s1  = (X - 1) & 3;

    #define ROWBASE(rc, tx) ((((rc) >> 2) * Wt + (tx)) * 16 + ((rc) & 3) * 4)
    const v4u A0 = *(const v4u*)(pp + ROWBASE(rY0, tx0));
    const v4u A1 = *(const v4u*)(pp + ROWBASE(rY1, tx0));
    v4u B0 = {0, 0, 0, 0}, B1 = {0, 0, 0, 0};
    if (s1 != 0) {                       // 75% of lanes
        B0 = *(const v4u*)(pp + ROWBASE(rY0, tx1));
        B1 = *(const v4u*)(pp + ROWBASE(rY1, tx1));
    }
    const int txA = cX >> 2;
    const int sA  = cX & 3;
    const int sB  = cX1 & 3;
    const bool nb = (cX1 >> 2) != txA;
    const v4u Tm = *(const v4u*)(pp + ROWBASE(rYm, txA));
    const v4u T2 = *(const v4u*)(pp + ROWBASE(rY2, txA));
    unsigned um = 0, u2 = 0;
    if (nb) {                            // 25% of lanes
        um = pp[ROWBASE(rYm, txA + 1)];
        u2 = pp[ROWBASE(rY2, txA + 1)];
    }
    #undef ROWBASE

    const unsigned tA = sel4(Tm.x, Tm.y, Tm.z, Tm.w, sA);
    const unsigned tG = sel4(T2.x, T2.y, T2.z, T2.w, sA);
    const unsigned tB = nb ? um : sel4(Tm.x, Tm.y, Tm.z, Tm.w, sB);
    const unsigned tH = nb ? u2 : sel4(T2.x, T2.y, T2.z, T2.w, sB);

    const unsigned tC = sel4(A0.x, A0.y, A0.z, A0.w, s1);
    const unsigned tI = sel4(A0.y, A0.z, A0.w, B0.x, s1);
    const unsigned tJ = sel4(A0.z, A0.w, B0.x, B0.y, s1);
    const unsigned tE = sel4(A0.w, B0.x, B0.y, B0.z, s1);
    const unsigned tD = sel4(A1.x, A1.y, A1.z, A1.w, s1);
    const unsigned tK = sel4(A1.y, A1.z, A1.w, B1.x, s1);
    const unsigned tL = sel4(A1.z, A1.w, B1.x, B1.y, s1);
    const unsigned tF = sel4(A1.w, B1.x, B1.y, B1.z, s1);

    float accR = 0.0f, accG = 0.0f, accB = 0.0f;
#define TAA_TAP(w_, t_) {                                                   \
    accR = fmaf(w_, (float)((t_) >> 21),           accR);                   \
    accG = fmaf(w_, (float)(((t_) >> 10) & 2047u), accG);                   \
    accB = fmaf(w_, (float)((t_) & 1023u),         accB); }
    TAA_TAP(wA, tA) TAA_TAP(wB, tB) TAA_TAP(wC, tC) TAA_TAP(wD, tD)
    TAA_TAP(wE, tE) TAA_TAP(wF, tF) TAA_TAP(wG, tG) TAA_TAP(wH, tH)
    TAA_TAP(wI, tI) TAA_TAP(wJ, tJ) TAA_TAP(wK, tK) TAA_TAP(wL, tL)
#undef TAA_TAP
    rep[0] = accR * (kInv2047 * inv_denom);
    rep[1] = accG * (kInv2047 * inv_denom);
    rep[2] = accB * (kInv1023 * inv_denom);
}

// ---- main TAA kernel: 2 adjacent pixels per thread ----
__global__ __launch_bounds__(128)
void taa_main2(const float* __restrict__ xin,
               const v2f* __restrict__ mv,
               const unsigned int* __restrict__ packed,
               float* __restrict__ out)
{
    // batch = bid & 3: round-robin block->XCD pins batch b to XCDs {b,b+4}.
    const int bid = blockIdx.x;            // 32400 blocks
    const int b   = bid & 3;
    const int r   = bid >> 2;              // 0..8099
    const int u   = r * 128 + threadIdx.x; // 2px-unit, 0..1036799; row=960 units (÷64)
    const int py  = u / 960;
    const int P   = (u - py * 960) * 2;    // even pixel
    const int p   = py * Wn + P;

    const v4f gg = __builtin_nontemporal_load((const v4f*)&mv[(size_t)b * HW + p]);

    const unsigned int* __restrict__ pp = packed + (size_t)b * HW;
    float rep0[3], rep1[3];
    bicubic_gather(pp, gg.x, gg.y, rep0);
    bicubic_gather(pp, gg.z, gg.w, rep1);

    // ---- 3x3 pool: float2 column loads + wave shuffles ----
    const int pym = max(py - 1, 0) * Wn;
    const int py0 = py * Wn;
    const int pyp = min(py + 1, Hn - 1) * Wn;
    const int lane = threadIdx.x & 63;

    float ctr0[3], ctr1[3];
    float mxlo[3], mxhi[3], mnlo[3], mnhi[3];
    #pragma unroll
    for (int c = 0; c < Cn; ++c) {
        const float* __restrict__ xp = xin + (size_t)(b * Cn + c) * HW;
        const v2f a = *(const v2f*)(xp + pym + P);
        const v2f m = *(const v2f*)(xp + py0 + P);
        const v2f z = *(const v2f*)(xp + pyp + P);
        ctr0[c] = m.x; ctr1[c] = m.y;
        mxlo[c] = fmaxf(fmaxf(a.x, m.x), z.x);
        mxhi[c] = fmaxf(fmaxf(a.y, m.y), z.y);
        mnlo[c] = fminf(fminf(a.x, m.x), z.x);
        mnhi[c] = fminf(fminf(a.y, m.y), z.y);
    }

    float lmx[3], lmn[3], rmx[3], rmn[3];   // left = col P-1, right = col P+2
    #pragma unroll
    for (int c = 0; c < Cn; ++c) {
        lmx[c] = __shfl_up(mxhi[c], 1);
        lmn[c] = __shfl_up(mnhi[c], 1);
        rmx[c] = __shfl_down(mxlo[c], 1);
        rmn[c] = __shfl_down(mnlo[c], 1);
    }

    // wave-edge lanes fetch their missing neighbor column directly
    if (lane == 0 || lane == 63) {
        const int ex = (lane == 0) ? max(P - 1, 0) : min(P + 2, Wn - 1);
        #pragma unroll
        for (int c = 0; c < Cn; ++c) {
            const float* __restrict__ xp = xin + (size_t)(b * Cn + c) * HW;
            const float e0 = xp[pym + ex];
            const float e1 = xp[py0 + ex];
            const float e2 = xp[pyp + ex];
            const float emax = fmaxf(fmaxf(e0, e1), e2);
            const float emin = fminf(fminf(e0, e1), e2);
            if (lane == 0) { lmx[c] = emax; lmn[c] = emin; }
            else           { rmx[c] = emax; rmn[c] = emin; }
        }
    }

    #pragma unroll
    for (int c = 0; c < Cn; ++c) {
        const float mx0 = fmaxf(fmaxf(lmx[c], mxlo[c]), mxhi[c]);
        const float mn0 = fminf(fminf(lmn[c], mnlo[c]), mnhi[c]);
        const float mx1 = fmaxf(fmaxf(mxlo[c], mxhi[c]), rmx[c]);
        const float mn1 = fminf(fminf(mnlo[c], mnhi[c]), rmn[c]);

        float rv0 = fminf(fmaxf(rep0[c], 0.0f), 1.0f);
        float rv1 = fminf(fmaxf(rep1[c], 0.0f), 1.0f);
        rv0 = fminf(fmaxf(rv0, mn0), mx0);
        rv1 = fminf(fmaxf(rv1, mn1), mx1);

        v2f o;
        o.x = kAlpha * ctr0[c] + (1.0f - kAlpha) * rv0;
        o.y = kAlpha * ctr1[c] + (1.0f - kAlpha) * rv1;
        __builtin_nontemporal_store(o, (v2f*)&out[(size_t)(b * Cn + c) * HW + p]);
    }
}

// ---- planar fallback (ws too small): 1 px/thread, 36 scalar gathers ----
__global__ __launch_bounds__(128)
void taa_fallback(const float* __restrict__ xin,
                  const v2f* __restrict__ mv,
                  const float* __restrict__ hist,
                  float* __restrict__ out)
{
    const int bid = blockIdx.x;
    const int b   = bid & 3;
    const int rr  = bid >> 2;
    const int py  = rr / 15;
    const int px  = (rr - py * 15) * 128 + threadIdx.x;
    const int p   = py * Wn + px;

    const v2f g = mv[(size_t)b * HW + p];
    const float posx = (g.x + 1.0f) * 0.5f * (float)Wn;
    const float posy = (g.y + 1.0f) * 0.5f * (float)Hn;
    const float Xf = floorf(posx - 0.5f);
    const float Yf = floorf(posy - 0.5f);
    const float fx = posx - (Xf + 0.5f);
    const float fy = posy - (Yf + 0.5f);
    const float fx2 = fx * fx, fx3 = fx2 * fx;
    const float w0x = -0.5f * fx3 + fx2 - 0.5f * fx;
    const float w1x =  1.5f * fx3 - 2.5f * fx2 + 1.0f;
    const float w2x = -1.5f * fx3 + 2.0f * fx2 + 0.5f * fx;
    const float w3x =  0.5f * fx3 - 0.5f * fx2;
    const float w12x = w1x + w2x, bxr = w2x / w12x;
    const float fy2 = fy * fy, fy3 = fy2 * fy;
    const float w0y = -0.5f * fy3 + fy2 - 0.5f * fy;
    const float w1y =  1.5f * fy3 - 2.5f * fy2 + 1.0f;
    const float w2y = -1.5f * fy3 + 2.0f * fy2 + 0.5f * fy;
    const float w3y =  0.5f * fy3 - 0.5f * fy2;
    const float w12y = w1y + w2y, byr = w2y / w12y;
    const int X = (int)Xf, Y = (int)Yf;
    const float vxm1 = ((unsigned)(X - 1) < (unsigned)Wn) ? 1.0f : 0.0f;
    const float vx0  = ((unsigned)(X    ) < (unsigned)Wn) ? 1.0f : 0.0f;
    const float vx1  = ((unsigned)(X + 1) < (unsigned)Wn) ? 1.0f : 0.0f;
    const float vx2  = ((unsigned)(X + 2) < (unsigned)Wn) ? 1.0f : 0.0f;
    const float vym1 = ((unsigned)(Y - 1) < (unsigned)Hn) ? 1.0f : 0.0f;
    const float vy0  = ((unsigned)(Y    ) < (unsigned)Hn) ? 1.0f : 0.0f;
    const float vy1  = ((unsigned)(Y + 1) < (unsigned)Hn) ? 1.0f : 0.0f;
    const float vy2  = ((unsigned)(Y + 2) < (unsigned)Hn) ? 1.0f : 0.0f;
    const float k1 = w12x * w0y, k2 = w0x * w12y, k3 = w3x * w12y;
    const float k4 = w12x * w3y, k5 = w12x * w12y;
    const float inv_denom = 1.0f / (k1 + k2 + k3 + k4 + k5);
    const float wxl = 1.0f - bxr, wxh = bxr, wyl = 1.0f - byr, wyh = byr;
    const float wA = k1 * wxl * (vym1 * vx0), wB = k1 * wxh * (vym1 * vx1);
    const float wC = k2 * wyl * (vxm1 * vy0), wD = k2 * wyh * (vxm1 * vy1);
    const float wE = k3 * wyl * (vx2 * vy0),  wF = k3 * wyh * (vx2 * vy1);
    const float wG = k4 * wxl * (vy2 * vx0),  wH = k4 * wxh * (vy2 * vx1);
    const float wI = k5 * wxl * wyl * (vx0 * vy0), wJ = k5 * wxh * wyl * (vx1 * vy0);
    const float wK = k5 * wxl * wyh * (vx0 * vy1), wL = k5 * wxh * wyh * (vx1 * vy1);
    const int cxm1 = min(max(X - 1, 0), Wn - 1), cx0 = min(max(X, 0), Wn - 1);
    const int cx1 = min(max(X + 1, 0), Wn - 1),  cx2 = min(max(X + 2, 0), Wn - 1);
    const int rym1 = min(max(Y - 1, 0), Hn - 1) * Wn, ry0 = min(max(Y, 0), Hn - 1) * Wn;
    const int ry1 = min(max(Y + 1, 0), Hn - 1) * Wn,  ry2 = min(max(Y + 2, 0), Hn - 1) * Wn;

    const int pym = max(py - 1, 0) * Wn;
    const int py0 = py * Wn;
    const int pyp = min(py + 1, Hn - 1) * Wn;
    const int pxm = max(px - 1, 0);
    const int pxp = min(px + 1, Wn - 1);

    #pragma unroll
    for (int c = 0; c < Cn; ++c) {
        const size_t plane = (size_t)(b * Cn + c) * HW;
        const float* __restrict__ hp = hist + plane;
        float acc = wA * hp[rym1 + cx0];
        acc = fmaf(wB, hp[rym1 + cx1], acc);
        acc = fmaf(wC, hp[ry0 + cxm1], acc);
        acc = fmaf(wD, hp[ry1 + cxm1], acc);
        acc = fmaf(wE, hp[ry0 + cx2], acc);
        acc = fmaf(wF, hp[ry1 + cx2], acc);
        acc = fmaf(wG, hp[ry2 + cx0], acc);
        acc = fmaf(wH, hp[ry2 + cx1], acc);
        acc = fmaf(wI, hp[ry0 + cx0], acc);
        acc = fmaf(wJ, hp[ry0 + cx1], acc);
        acc = fmaf(wK, hp[ry1 + cx0], acc);
        acc = fmaf(wL, hp[ry1 + cx1], acc);
        float rv = fminf(fmaxf(acc * inv_denom, 0.0f), 1.0f);

        const float* __restrict__ xp = xin + plane;
        const float r0a = xp[pym + pxm], r0b = xp[pym + px], r0c = xp[pym + pxp];
        const float r1a = xp[py0 + pxm], r1b = xp[py0 + px], r1c = xp[py0 + pxp];
        const float r2a = xp[pyp + pxm], r2b = xp[pyp + px], r2c = xp[pyp + pxp];
        const float mx = fmaxf(fmaxf(fmaxf(r0a, r0b), fmaxf(r0c, r1a)),
                               fmaxf(fmaxf(r1b, r1c), fmaxf(fmaxf(r2a, r2b), r2c)));
        const float mn = fminf(fminf(fminf(r0a, r0b), fminf(r0c, r1a)),
                               fminf(fminf(r1b, r1c), fminf(fminf(r2a, r2b), r2c)));
        rv = fminf(fmaxf(rv, mn), mx);
        out[plane + p] = kAlpha * r1b + (1.0f - kAlpha) * rv;
    }
}

} // namespace

extern "C" void kernel_launch(void* const* d_in, const int* in_sizes, int n_in,
                              void* d_out, int out_size, void* d_ws, size_t ws_size,
                              hipStream_t stream) {
    const float* x    = (const float*)d_in[0];
    const v2f*   mv   = (const v2f*)d_in[1];
    const float* hist = (const float*)d_in[2];
    float* outp = (float*)d_out;

    const size_t packed_bytes = (size_t)Bn * HW * 4;

    if (ws_size >= packed_bytes) {
        unsigned int* packed = (unsigned int*)d_ws;
        pack_tiled<<<Bn * Ht * 15, 128, 0, stream>>>(hist, packed);
        // 2 px/thread: Bn*HW/2 threads, 128/block -> 32400 blocks
        taa_main2<<<Bn * HW / 256, 128, 0, stream>>>(x, mv, packed, outp);
    } else {
        taa_fallback<<<(Wn / 128) * Hn * Bn, 128, 0, stream>>>(x, mv, hist, outp);
    }
}